// Round 1
// baseline (219.649 us; speedup 1.0000x reference)
//
#include <hip/hip_runtime.h>

#define D 64
#define K 1024
#define NTOK 65536          // 64 * 32 * 32 tokens
#define HWSZ 1024           // 32*32
#define TPB 256
#define TOKS_PER_BLOCK 64
#define NBLK (NTOK / TOKS_PER_BLOCK)   // 1024
#define QUANT_ELEMS 4194304            // 64*64*32*32
#define TAU 2e-3f

// ---------------- prep: zero loss accumulator, compute ||e_k||^2 ----------------
__global__ void vq_prep(const float* __restrict__ emb, double* __restrict__ acc,
                        float* __restrict__ enorm) {
    int k = blockIdx.x * blockDim.x + threadIdx.x;
    if (k == 0) *acc = 0.0;
    if (k < K) {
        const float4* e = reinterpret_cast<const float4*>(emb + (size_t)k * D);
        float s = 0.f;
#pragma unroll
        for (int i = 0; i < 16; ++i) {
            float4 v = e[i];
            s += v.x * v.x + v.y * v.y + v.z * v.z + v.w * v.w;
        }
        enorm[k] = s;
    }
}

// ---------------- main: argmin + quantized write + loss ----------------
__global__ __launch_bounds__(TPB, 4) void vq_main(const float* __restrict__ x,
                                                  const float* __restrict__ emb,
                                                  const float* __restrict__ enorm,
                                                  float* __restrict__ out,
                                                  double* __restrict__ loss_acc) {
    const int tid = threadIdx.x;
    const int lane = tid & 63;
    // chunk is wave-uniform; readfirstlane makes that provable -> scalar loads of emb
    const int chunk = __builtin_amdgcn_readfirstlane(tid >> 6);

    const int tglob = blockIdx.x * TOKS_PER_BLOCK + lane;  // token id
    const int b = tglob >> 10;
    const int hw = tglob & (HWSZ - 1);

    // x[b][d][hw], d-stride = 1024 floats; coalesced across lanes for each d
    const float* xb = x + (size_t)b * (D * HWSZ) + hw;
    float xr[D];
#pragma unroll
    for (int d = 0; d < D; ++d) xr[d] = xb[(size_t)d * HWSZ];

    // ---- scan this wave's 256-code chunk: score = ||e||^2 - 2 x.e ----
    float min1 = 1e30f, min2 = 1e30f;
    int bidx = 0;
    const int kbase = chunk * (K / 4);
    for (int k0 = 0; k0 < K / 4; k0 += 2) {
        const float* e0 = emb + (size_t)(kbase + k0) * D;
        const float* e1 = e0 + D;
        float dot0 = 0.f, dot1 = 0.f;
#pragma unroll
        for (int d = 0; d < D; d += 4) {
            float4 a = *reinterpret_cast<const float4*>(e0 + d);
            float4 c = *reinterpret_cast<const float4*>(e1 + d);
            dot0 = fmaf(xr[d + 0], a.x, dot0);
            dot0 = fmaf(xr[d + 1], a.y, dot0);
            dot0 = fmaf(xr[d + 2], a.z, dot0);
            dot0 = fmaf(xr[d + 3], a.w, dot0);
            dot1 = fmaf(xr[d + 0], c.x, dot1);
            dot1 = fmaf(xr[d + 1], c.y, dot1);
            dot1 = fmaf(xr[d + 2], c.z, dot1);
            dot1 = fmaf(xr[d + 3], c.w, dot1);
        }
        float s0 = fmaf(-2.f, dot0, enorm[kbase + k0]);
        float s1 = fmaf(-2.f, dot1, enorm[kbase + k0 + 1]);
        if (s0 < min1) { min2 = min1; min1 = s0; bidx = kbase + k0; }
        else if (s0 < min2) { min2 = s0; }
        if (s1 < min1) { min2 = min1; min1 = s1; bidx = kbase + k0 + 1; }
        else if (s1 < min2) { min2 = s1; }
    }

    // ---- merge the 4 chunks per token via LDS ----
    __shared__ float sm1[4][TOKS_PER_BLOCK];
    __shared__ float sm2[4][TOKS_PER_BLOCK];
    __shared__ int sidx[4][TOKS_PER_BLOCK];
    __shared__ int sfinal[TOKS_PER_BLOCK];
    __shared__ int s_flaglist[TOKS_PER_BLOCK];
    __shared__ int s_nflag;
    __shared__ double rbv[4];
    __shared__ int rbi[4];
    __shared__ double lred[4];

    if (tid == 0) s_nflag = 0;
    sm1[chunk][lane] = min1;
    sm2[chunk][lane] = min2;
    sidx[chunk][lane] = bidx;
    __syncthreads();

    if (tid < TOKS_PER_BLOCK) {
        float m1 = sm1[0][tid], m2 = sm2[0][tid];
        int mi = sidx[0][tid];
#pragma unroll
        for (int c = 1; c < 4; ++c) {
            float a1 = sm1[c][tid], a2 = sm2[c][tid];
            int ai = sidx[c][tid];
            if (a1 < m1) { m2 = fminf(m1, a2); m1 = a1; mi = ai; }
            else { m2 = fminf(m2, a1); }
        }
        sfinal[tid] = mi;
        if (m2 - m1 < TAU) {
            int p = atomicAdd(&s_nflag, 1);
            s_flaglist[p] = tid;
        }
    }
    __syncthreads();

    // ---- rare: fp64 full rescore for near-tie tokens (block-cooperative) ----
    const int nf = s_nflag;
    for (int f = 0; f < nf; ++f) {
        const int t = s_flaglist[f];
        const int tg = blockIdx.x * TOKS_PER_BLOCK + t;
        const float* xf = x + (size_t)(tg >> 10) * (D * HWSZ) + (tg & (HWSZ - 1));
        double bv = 1e300;
        int bi = 0x7fffffff;
        for (int kk = tid; kk < K; kk += TPB) {
            const float* ek = emb + (size_t)kk * D;
            double a = 0.0;
#pragma unroll 8
            for (int d = 0; d < D; ++d) {
                double diff = (double)xf[(size_t)d * HWSZ] - (double)ek[d];
                a += diff * diff;
            }
            if (a < bv || (a == bv && kk < bi)) { bv = a; bi = kk; }
        }
        for (int off = 32; off; off >>= 1) {
            double ov = __shfl_down(bv, off);
            int oi = __shfl_down(bi, off);
            if (ov < bv || (ov == bv && oi < bi)) { bv = ov; bi = oi; }
        }
        if (lane == 0) { rbv[chunk] = bv; rbi[chunk] = bi; }
        __syncthreads();
        if (tid == 0) {
            double fv = rbv[0]; int fi = rbi[0];
#pragma unroll
            for (int c = 1; c < 4; ++c) {
                if (rbv[c] < fv || (rbv[c] == fv && rbi[c] < fi)) { fv = rbv[c]; fi = rbi[c]; }
            }
            sfinal[t] = fi;
        }
        __syncthreads();
    }

    // ---- write quantized (NCHW) + fp64 loss partial ----
    // thread handles token `lane`, dims [chunk*16, chunk*16+16)
    const int idx = sfinal[lane];
    const int q = chunk;
    const float* eq = emb + (size_t)idx * D + q * 16;
    float* ob = out + (size_t)b * (D * HWSZ) + (size_t)(q * 16) * HWSZ + hw;
    double lacc = 0.0;
#pragma unroll
    for (int j = 0; j < 16; j += 4) {
        float4 e4 = *reinterpret_cast<const float4*>(eq + j);
        ob[(size_t)(j + 0) * HWSZ] = e4.x;
        ob[(size_t)(j + 1) * HWSZ] = e4.y;
        ob[(size_t)(j + 2) * HWSZ] = e4.z;
        ob[(size_t)(j + 3) * HWSZ] = e4.w;
        double d0 = (double)xr[q * 16 + j + 0] - (double)e4.x; lacc += d0 * d0;
        double d1 = (double)xr[q * 16 + j + 1] - (double)e4.y; lacc += d1 * d1;
        double d2 = (double)xr[q * 16 + j + 2] - (double)e4.z; lacc += d2 * d2;
        double d3 = (double)xr[q * 16 + j + 3] - (double)e4.w; lacc += d3 * d3;
    }
    for (int off = 32; off; off >>= 1) lacc += __shfl_down(lacc, off);
    if (lane == 0) lred[chunk] = lacc;
    __syncthreads();
    if (tid == 0) atomicAdd(loss_acc, lred[0] + lred[1] + lred[2] + lred[3]);
}

// ---------------- finalize: loss scalar ----------------
__global__ void vq_finalize(const double* __restrict__ acc, float* __restrict__ out) {
    // loss = q_latent + 0.25*e_latent = 1.25 * mean((q - x)^2)
    out[QUANT_ELEMS] = (float)(1.25 * (*acc) / (double)QUANT_ELEMS);
}

extern "C" void kernel_launch(void* const* d_in, const int* in_sizes, int n_in,
                              void* d_out, int out_size, void* d_ws, size_t ws_size,
                              hipStream_t stream) {
    const float* x = (const float*)d_in[0];
    const float* emb = (const float*)d_in[1];
    float* out = (float*)d_out;
    double* acc = (double*)d_ws;
    float* enorm = (float*)((char*)d_ws + 256);

    vq_prep<<<16, 64, 0, stream>>>(emb, acc, enorm);
    vq_main<<<NBLK, TPB, 0, stream>>>(x, emb, enorm, out, acc);
    vq_finalize<<<1, 1, 0, stream>>>(acc, out);
}

// Round 3
// 67.214 us; speedup vs baseline: 3.2679x; 3.2679x over previous
//
#include <hip/hip_runtime.h>

#define D 64
#define K 1024
#define HWSZ 1024
#define TPB 256
#define TOKS_PER_BLOCK 128
#define NBLK 512                       // 65536 / 128
#define QUANT_ELEMS 4194304            // 64*64*32*32
#define TAU 2e-3f

typedef __attribute__((ext_vector_type(8))) short short8;
typedef __attribute__((ext_vector_type(4))) float floatx4;

union Frag { short8 v; unsigned u[4]; };

#define MFMA(a, b, c) __builtin_amdgcn_mfma_f32_16x16x32_bf16((a), (b), (c), 0, 0, 0)

// round f32 -> bf16 (rne), return as f32 bit pattern (low 16 zeroed)
static __device__ inline unsigned bf16_hi_bits(float f) {
    unsigned u = __builtin_bit_cast(unsigned, f);
    return (u + 0x7fffu + ((u >> 16) & 1u)) & 0xffff0000u;
}

// split (a,b) into bf16 hi pair and bf16 lo (residual) pair, each packed in one u32
static __device__ inline void split2(float a, float b, unsigned& hi, unsigned& lo) {
    unsigned ha = bf16_hi_bits(a);
    unsigned hb = bf16_hi_bits(b);
    hi = hb | (ha >> 16);
    float ra = a - __builtin_bit_cast(float, ha);
    float rb = b - __builtin_bit_cast(float, hb);
    lo = bf16_hi_bits(rb) | (bf16_hi_bits(ra) >> 16);
}

__global__ __launch_bounds__(TPB, 2) void vq_main(const float* __restrict__ x,
                                                  const float* __restrict__ emb,
                                                  float* __restrict__ out,
                                                  double* __restrict__ loss_acc) {
    const int tid = threadIdx.x;
    const int lane = tid & 63;
    const int w = __builtin_amdgcn_readfirstlane(tid >> 6);  // wave id 0..3
    const int lhi = lane >> 4;   // 0..3
    const int llo = lane & 15;   // 0..15

    __shared__ short8 fragbuf[4096];      // 64 frags x 64 lanes x 16B = 64 KB
    __shared__ float enorm_lds[256];
    __shared__ int sfinal[TOKS_PER_BLOCK];
    __shared__ int s_flaglist[TOKS_PER_BLOCK];
    __shared__ int s_nflag;
    __shared__ double rbv[4];
    __shared__ int rbi[4];
    __shared__ double lred[4];

    if (tid == 0) s_nflag = 0;

    const int tb = blockIdx.x * TOKS_PER_BLOCK;  // global token base
    const int bb = tb >> 10;                     // batch index
    const int hwb = tb & 1023;                   // hw base (multiple of 128)
    const float* xbase = x + (size_t)bb * (D * HWSZ);

    // ---- load & convert A fragments (32 tokens per wave, held in regs) ----
    // A row (token-in-group) = llo ; k = lhi*8 + j ; d = kh*32 + k
    Frag ah[2][2], al[2][2];
#pragma unroll
    for (int r = 0; r < 2; ++r) {
        const int hw = hwb + w * 32 + r * 16 + llo;
#pragma unroll
        for (int kh = 0; kh < 2; ++kh) {
            const float* xp = xbase + (size_t)(kh * 32 + lhi * 8) * HWSZ + hw;
            float v[8];
#pragma unroll
            for (int j = 0; j < 8; ++j) v[j] = xp[(size_t)j * HWSZ];
#pragma unroll
            for (int p = 0; p < 4; ++p)
                split2(v[2 * p], v[2 * p + 1], ah[r][kh].u[p], al[r][kh].u[p]);
        }
    }

    float m1[2][4], m2[2][4];
    int bidx[2][4];
#pragma unroll
    for (int r = 0; r < 2; ++r)
#pragma unroll
        for (int i = 0; i < 4; ++i) { m1[r][i] = 1e30f; m2[r][i] = 1e30f; bidx[r][i] = 0; }

    // ---- chunk loop: 4 chunks x 256 codes ----
    for (int ch = 0; ch < 4; ++ch) {
        // stage: each wave converts 4 tiles (16 codes each) into LDS frag layout
#pragma unroll
        for (int tt = 0; tt < 4; ++tt) {
            const int tc = tt * 4 + w;                 // chunk-local tile 0..15
            const int code = (ch * 16 + tc) * 16 + llo;
            const float* ep = emb + (size_t)code * D + lhi * 8;
            floatx4 e0 = *(const floatx4*)(ep);
            floatx4 e1 = *(const floatx4*)(ep + 4);
            floatx4 e2 = *(const floatx4*)(ep + 32);
            floatx4 e3 = *(const floatx4*)(ep + 36);
            Frag h0, l0, h1, l1;
            split2(e0.x, e0.y, h0.u[0], l0.u[0]); split2(e0.z, e0.w, h0.u[1], l0.u[1]);
            split2(e1.x, e1.y, h0.u[2], l0.u[2]); split2(e1.z, e1.w, h0.u[3], l0.u[3]);
            split2(e2.x, e2.y, h1.u[0], l1.u[0]); split2(e2.z, e2.w, h1.u[1], l1.u[1]);
            split2(e3.x, e3.y, h1.u[2], l1.u[2]); split2(e3.z, e3.w, h1.u[3], l1.u[3]);
            fragbuf[(tc * 4 + 0) * 64 + lane] = h0.v;
            fragbuf[(tc * 4 + 1) * 64 + lane] = h1.v;
            fragbuf[(tc * 4 + 2) * 64 + lane] = l0.v;
            fragbuf[(tc * 4 + 3) * 64 + lane] = l1.v;
            // ||e||^2 partial over this lane's 16 dims, butterfly over lhi
            float s = e0.x * e0.x + e0.y * e0.y + e0.z * e0.z + e0.w * e0.w
                    + e1.x * e1.x + e1.y * e1.y + e1.z * e1.z + e1.w * e1.w
                    + e2.x * e2.x + e2.y * e2.y + e2.z * e2.z + e2.w * e2.w
                    + e3.x * e3.x + e3.y * e3.y + e3.z * e3.z + e3.w * e3.w;
            s += __shfl_xor(s, 16);
            s += __shfl_xor(s, 32);
            if (lhi == 0) enorm_lds[tc * 16 + llo] = s;
        }
        __syncthreads();

        const int cbase = ch * 256;
#pragma unroll 4
        for (int tc = 0; tc < 16; ++tc) {
            short8 bh0 = fragbuf[(tc * 4 + 0) * 64 + lane];
            short8 bh1 = fragbuf[(tc * 4 + 1) * 64 + lane];
            short8 bl0 = fragbuf[(tc * 4 + 2) * 64 + lane];
            short8 bl1 = fragbuf[(tc * 4 + 3) * 64 + lane];
            const float en = enorm_lds[tc * 16 + llo];
            const int inew = cbase + tc * 16 + llo;
#pragma unroll
            for (int r = 0; r < 2; ++r) {
                floatx4 acc = {0.f, 0.f, 0.f, 0.f};
                acc = MFMA(ah[r][0].v, bh0, acc);
                acc = MFMA(ah[r][1].v, bh1, acc);
                acc = MFMA(ah[r][0].v, bl0, acc);
                acc = MFMA(ah[r][1].v, bl1, acc);
                acc = MFMA(al[r][0].v, bh0, acc);
                acc = MFMA(al[r][1].v, bh1, acc);
#pragma unroll
                for (int i = 0; i < 4; ++i) {
                    float s = fmaf(-2.f, acc[i], en);
                    float t = fmaxf(m1[r][i], s);
                    m2[r][i] = fminf(m2[r][i], t);
                    bool c = s < m1[r][i];
                    bidx[r][i] = c ? inew : bidx[r][i];
                    m1[r][i] = fminf(m1[r][i], s);
                }
            }
        }
        __syncthreads();
    }

    // ---- cross-lane reduce over the 16 col-lanes; C row = lhi*4+i ----
#pragma unroll
    for (int r = 0; r < 2; ++r)
#pragma unroll
        for (int i = 0; i < 4; ++i) {
            float a1 = m1[r][i], a2 = m2[r][i];
            int ai = bidx[r][i];
#pragma unroll
            for (int sft = 1; sft < 16; sft <<= 1) {
                float o1 = __shfl_xor(a1, sft);
                float o2 = __shfl_xor(a2, sft);
                int oi = __shfl_xor(ai, sft);
                float big = fmaxf(a1, o1);
                a2 = fminf(fminf(a2, o2), big);
                if (o1 < a1 || (o1 == a1 && oi < ai)) { a1 = o1; ai = oi; }
            }
            if (llo == 0) {
                int tl = w * 32 + r * 16 + lhi * 4 + i;
                sfinal[tl] = ai;
                if (a2 - a1 < TAU) {
                    int p = atomicAdd(&s_nflag, 1);
                    s_flaglist[p] = tl;
                }
            }
        }
    __syncthreads();

    // ---- rare: fp64 full rescore for near-tie tokens (block-cooperative) ----
    const int nf = s_nflag;
    for (int f = 0; f < nf; ++f) {
        const int t = s_flaglist[f];
        const int tg = tb + t;
        const float* xf = x + (size_t)(tg >> 10) * (D * HWSZ) + (tg & 1023);
        double bv = 1e300;
        int bi = 0x7fffffff;
        for (int kk = tid; kk < K; kk += TPB) {
            const float* ek = emb + (size_t)kk * D;
            double a = 0.0;
#pragma unroll 8
            for (int d = 0; d < D; ++d) {
                double diff = (double)xf[(size_t)d * HWSZ] - (double)ek[d];
                a += diff * diff;
            }
            if (a < bv || (a == bv && kk < bi)) { bv = a; bi = kk; }
        }
        for (int off = 32; off; off >>= 1) {
            double ov = __shfl_down(bv, off);
            int oi = __shfl_down(bi, off);
            if (ov < bv || (ov == bv && oi < bi)) { bv = ov; bi = oi; }
        }
        if (lane == 0) { rbv[w] = bv; rbi[w] = bi; }
        __syncthreads();
        if (tid == 0) {
            double fv = rbv[0];
            int fi = rbi[0];
#pragma unroll
            for (int c = 1; c < 4; ++c)
                if (rbv[c] < fv || (rbv[c] == fv && rbi[c] < fi)) { fv = rbv[c]; fi = rbi[c]; }
            sfinal[t] = fi;
        }
        __syncthreads();
    }

    // ---- epilogue: write quantized (NCHW) + fp64 loss ----
    const int hl = tid & 127;        // token-local
    const int dh = tid >> 7;         // d-half: 0 or 1
    const int hw = hwb + hl;
    const int qidx = sfinal[hl];
    const float* eq = emb + (size_t)qidx * D + dh * 32;
    const float* xp = xbase + (size_t)(dh * 32) * HWSZ + hw;
    float* op = out + (size_t)bb * (D * HWSZ) + (size_t)(dh * 32) * HWSZ + hw;
    double lacc = 0.0;
#pragma unroll
    for (int j0 = 0; j0 < 32; j0 += 4) {
        floatx4 e4 = *(const floatx4*)(eq + j0);
        op[(size_t)(j0 + 0) * HWSZ] = e4.x;
        op[(size_t)(j0 + 1) * HWSZ] = e4.y;
        op[(size_t)(j0 + 2) * HWSZ] = e4.z;
        op[(size_t)(j0 + 3) * HWSZ] = e4.w;
        double d0 = (double)xp[(size_t)(j0 + 0) * HWSZ] - (double)e4.x; lacc += d0 * d0;
        double d1 = (double)xp[(size_t)(j0 + 1) * HWSZ] - (double)e4.y; lacc += d1 * d1;
        double d2 = (double)xp[(size_t)(j0 + 2) * HWSZ] - (double)e4.z; lacc += d2 * d2;
        double d3 = (double)xp[(size_t)(j0 + 3) * HWSZ] - (double)e4.w; lacc += d3 * d3;
    }
    for (int off = 32; off; off >>= 1) lacc += __shfl_down(lacc, off);
    if (lane == 0) lred[w] = lacc;
    __syncthreads();
    if (tid == 0) atomicAdd(loss_acc, lred[0] + lred[1] + lred[2] + lred[3]);
}

__global__ void vq_finalize(const double* __restrict__ acc, float* __restrict__ out) {
    out[QUANT_ELEMS] = (float)(1.25 * (*acc) / (double)QUANT_ELEMS);
}

extern "C" void kernel_launch(void* const* d_in, const int* in_sizes, int n_in,
                              void* d_out, int out_size, void* d_ws, size_t ws_size,
                              hipStream_t stream) {
    const float* x = (const float*)d_in[0];
    const float* emb = (const float*)d_in[1];
    float* out = (float*)d_out;
    double* acc = (double*)d_ws;

    (void)hipMemsetAsync(d_ws, 0, 8, stream);
    vq_main<<<NBLK, TPB, 0, stream>>>(x, emb, out, acc);
    vq_finalize<<<1, 1, 0, stream>>>(acc, out);
}

// Round 4
// 61.317 us; speedup vs baseline: 3.5822x; 1.0962x over previous
//
#include <hip/hip_runtime.h>

#define D 64
#define K 1024
#define HWSZ 1024
#define TPB 256
#define TOKS_PER_BLOCK 64
#define NBLK 1024                      // 65536 / 64
#define QUANT_ELEMS 4194304            // 64*64*32*32
#define TAU_H 1e-3f                    // gap threshold in halved-score domain (== 2e-3 full)
#define NSTEPS 16                      // 64 code-tiles, 4 per step

typedef __attribute__((ext_vector_type(8))) short short8;
typedef __attribute__((ext_vector_type(4))) float floatx4;

union Frag { short8 v; unsigned u[4]; };

#define MFMA(a, b, c) __builtin_amdgcn_mfma_f32_16x16x32_bf16((a), (b), (c), 0, 0, 0)

// round f32 -> bf16 (rne), return as f32 bit pattern (low 16 zeroed)
static __device__ inline unsigned bf16_hi_bits(float f) {
    unsigned u = __builtin_bit_cast(unsigned, f);
    return (u + 0x7fffu + ((u >> 16) & 1u)) & 0xffff0000u;
}

// split (a,b) into bf16 hi pair and bf16 lo (residual) pair, each packed in one u32
static __device__ inline void split2(float a, float b, unsigned& hi, unsigned& lo) {
    unsigned ha = bf16_hi_bits(a);
    unsigned hb = bf16_hi_bits(b);
    hi = hb | (ha >> 16);
    float ra = a - __builtin_bit_cast(float, ha);
    float rb = b - __builtin_bit_cast(float, hb);
    lo = bf16_hi_bits(rb) | (bf16_hi_bits(ra) >> 16);
}

// ---------------- prep: convert codebook to MFMA B-frag layout + 0.5||e||^2 ----------------
// G[tile][frag][lane] : tile = 16-code group (64 tiles), frag in {h_kh0, h_kh1, l_kh0, l_kh1}
// B lane mapping: code = lane&15, k = (lane>>4)*8 + j, d = kh*32 + k
__global__ void vq_prep(const float* __restrict__ emb, double* __restrict__ acc,
                        float* __restrict__ enorm_h, short8* __restrict__ G) {
    const int tid = threadIdx.x;
    const int lane = tid & 63;
    const int w = tid >> 6;
    const int lhi = lane >> 4, llo = lane & 15;
    const int tile = blockIdx.x * 4 + w;
    if (blockIdx.x == 0 && tid == 0) *acc = 0.0;

    const int code = tile * 16 + llo;
    const float* ep = emb + (size_t)code * D + lhi * 8;
    floatx4 e0 = *(const floatx4*)(ep);
    floatx4 e1 = *(const floatx4*)(ep + 4);
    floatx4 e2 = *(const floatx4*)(ep + 32);
    floatx4 e3 = *(const floatx4*)(ep + 36);
    Frag h0, l0, h1, l1;
    split2(e0.x, e0.y, h0.u[0], l0.u[0]); split2(e0.z, e0.w, h0.u[1], l0.u[1]);
    split2(e1.x, e1.y, h0.u[2], l0.u[2]); split2(e1.z, e1.w, h0.u[3], l0.u[3]);
    split2(e2.x, e2.y, h1.u[0], l1.u[0]); split2(e2.z, e2.w, h1.u[1], l1.u[1]);
    split2(e3.x, e3.y, h1.u[2], l1.u[2]); split2(e3.z, e3.w, h1.u[3], l1.u[3]);
    G[(tile * 4 + 0) * 64 + lane] = h0.v;
    G[(tile * 4 + 1) * 64 + lane] = h1.v;
    G[(tile * 4 + 2) * 64 + lane] = l0.v;
    G[(tile * 4 + 3) * 64 + lane] = l1.v;

    float s = e0.x * e0.x + e0.y * e0.y + e0.z * e0.z + e0.w * e0.w
            + e1.x * e1.x + e1.y * e1.y + e1.z * e1.z + e1.w * e1.w
            + e2.x * e2.x + e2.y * e2.y + e2.z * e2.z + e2.w * e2.w
            + e3.x * e3.x + e3.y * e3.y + e3.z * e3.z + e3.w * e3.w;
    s += __shfl_xor(s, 16);
    s += __shfl_xor(s, 32);
    if (lhi == 0) enorm_h[code] = 0.5f * s;
}

// ---------------- main ----------------
__global__ __launch_bounds__(TPB, 4) void vq_main(const float* __restrict__ x,
                                                  const float* __restrict__ emb,
                                                  const float* __restrict__ enorm_h,
                                                  const short8* __restrict__ G,
                                                  float* __restrict__ out,
                                                  double* __restrict__ loss_acc) {
    const int tid = threadIdx.x;
    const int lane = tid & 63;
    const int w = __builtin_amdgcn_readfirstlane(tid >> 6);
    const int lhi = lane >> 4, llo = lane & 15;

    __shared__ short8 fb[2][1024];        // 2 x (4 tiles x 4 frags x 64 lanes) = 32 KB
    __shared__ float en_lds[K];           // 4 KB
    __shared__ float xnorm_lds[TOKS_PER_BLOCK];
    __shared__ int sfinal[TOKS_PER_BLOCK];
    __shared__ int s_flaglist[TOKS_PER_BLOCK];
    __shared__ int s_nflag;
    __shared__ double rbv[4];
    __shared__ int rbi[4];
    __shared__ double lred[4];

    if (tid == 0) s_nflag = 0;

    const int tb = blockIdx.x * TOKS_PER_BLOCK;
    const int bb = tb >> 10;
    const int hwb = tb & 1023;
    const float* xbase = x + (size_t)bb * (D * HWSZ);

    // stage first chunk ASAP
    {
        const short8* src = G + (size_t)(w * 4) * 64 + lane;
#pragma unroll
        for (int j = 0; j < 4; ++j)
            __builtin_amdgcn_global_load_lds(
                (const __attribute__((address_space(1))) void*)(src + (size_t)j * 64),
                (__attribute__((address_space(3))) void*)&fb[0][(w * 4 + j) * 64],
                16, 0, 0);
    }

    // ---- load & convert A fragments (16 tokens per wave) ----
    // A: row(token) = llo, k = lhi*8 + j, d = kh*32 + k
    Frag ah[2], al[2];
    float xn = 0.f;
    const int hw = hwb + w * 16 + llo;
#pragma unroll
    for (int kh = 0; kh < 2; ++kh) {
        const float* xp = xbase + (size_t)(kh * 32 + lhi * 8) * HWSZ + hw;
        float v[8];
#pragma unroll
        for (int j = 0; j < 8; ++j) { v[j] = xp[(size_t)j * HWSZ]; xn += v[j] * v[j]; }
#pragma unroll
        for (int p = 0; p < 4; ++p)
            split2(v[2 * p], v[2 * p + 1], ah[kh].u[p], al[kh].u[p]);
    }
    xn += __shfl_xor(xn, 16);
    xn += __shfl_xor(xn, 32);
    if (lhi == 0) xnorm_lds[w * 16 + llo] = xn;

    for (int i = tid; i < K; i += TPB) en_lds[i] = enorm_h[i];

    float m1[4], m2[4];
    int bidx[4];
#pragma unroll
    for (int i = 0; i < 4; ++i) { m1[i] = 1e30f; m2[i] = 1e30f; bidx[i] = 0; }

    __syncthreads();

    // ---- main scan: 16 steps x 4 tiles, double-buffered ----
    int cur = 0;
    for (int step = 0; step < NSTEPS; ++step) {
        if (step < NSTEPS - 1) {
            const short8* src = G + (size_t)(step + 1) * 1024 + (size_t)(w * 4) * 64 + lane;
#pragma unroll
            for (int j = 0; j < 4; ++j)
                __builtin_amdgcn_global_load_lds(
                    (const __attribute__((address_space(1))) void*)(src + (size_t)j * 64),
                    (__attribute__((address_space(3))) void*)&fb[cur ^ 1][(w * 4 + j) * 64],
                    16, 0, 0);
        }
#pragma unroll
        for (int tc = 0; tc < 4; ++tc) {
            const int tile = step * 4 + tc;
            short8 bh0 = fb[cur][(tc * 4 + 0) * 64 + lane];
            short8 bh1 = fb[cur][(tc * 4 + 1) * 64 + lane];
            short8 bl0 = fb[cur][(tc * 4 + 2) * 64 + lane];
            short8 bl1 = fb[cur][(tc * 4 + 3) * 64 + lane];
            const float en = en_lds[tile * 16 + llo];
            floatx4 accA = {0.f, 0.f, 0.f, 0.f};
            floatx4 accB = {0.f, 0.f, 0.f, 0.f};
            accA = MFMA(ah[0].v, bh0, accA);
            accB = MFMA(ah[1].v, bh1, accB);
            accA = MFMA(al[0].v, bh0, accA);
            accB = MFMA(al[1].v, bh1, accB);
            accA = MFMA(ah[0].v, bl0, accA);
            accB = MFMA(ah[1].v, bl1, accB);
#pragma unroll
            for (int i = 0; i < 4; ++i) {
                float s = en - accA[i] - accB[i];   // 0.5*||e||^2 - x.e
                float m1o = m1[i];
                bool c = s < m1o;
                m2[i] = __builtin_amdgcn_fmed3f(s, m1o, m2[i]);
                m1[i] = c ? s : m1o;
                bidx[i] = c ? tile : bidx[i];
            }
        }
        __syncthreads();
        cur ^= 1;
    }

    // ---- cross-lane argmin reduce over the 16 col-lanes; C row = lhi*4+i ----
    double lacc = 0.0;
#pragma unroll
    for (int i = 0; i < 4; ++i) {
        float a1 = m1[i], a2 = m2[i];
        int ai = bidx[i] * 16 + llo;
#pragma unroll
        for (int sft = 1; sft < 16; sft <<= 1) {
            float o1 = __shfl_xor(a1, sft);
            float o2 = __shfl_xor(a2, sft);
            int oi = __shfl_xor(ai, sft);
            float big = fmaxf(a1, o1);
            a2 = fminf(fminf(a2, o2), big);
            if (o1 < a1 || (o1 == a1 && oi < ai)) { a1 = o1; ai = oi; }
        }
        if (llo == 0) {
            const int tl = w * 16 + lhi * 4 + i;
            sfinal[tl] = ai;
            lacc += (double)(xnorm_lds[tl] + 2.0f * a1);   // ||x||^2 + 2*s_min
            if (a2 - a1 < TAU_H) {
                int p = atomicAdd(&s_nflag, 1);
                s_flaglist[p] = tl;
            }
        }
    }
    __syncthreads();

    // ---- rare: fp64 full rescore for near-tie tokens (block-cooperative) ----
    const int nf = s_nflag;
    for (int f = 0; f < nf; ++f) {
        const int t = s_flaglist[f];
        const int tg = tb + t;
        const float* xf = x + (size_t)(tg >> 10) * (D * HWSZ) + (tg & 1023);
        double bv = 1e300;
        int bi = 0x7fffffff;
        for (int kk = tid; kk < K; kk += TPB) {
            const float* ek = emb + (size_t)kk * D;
            double a = 0.0;
#pragma unroll 8
            for (int d = 0; d < D; ++d) {
                double diff = (double)xf[(size_t)d * HWSZ] - (double)ek[d];
                a += diff * diff;
            }
            if (a < bv || (a == bv && kk < bi)) { bv = a; bi = kk; }
        }
        for (int off = 32; off; off >>= 1) {
            double ov = __shfl_down(bv, off);
            int oi = __shfl_down(bi, off);
            if (ov < bv || (ov == bv && oi < bi)) { bv = ov; bi = oi; }
        }
        if (lane == 0) { rbv[w] = bv; rbi[w] = bi; }
        __syncthreads();
        if (tid == 0) {
            double fv = rbv[0];
            int fi = rbi[0];
#pragma unroll
            for (int c = 1; c < 4; ++c)
                if (rbv[c] < fv || (rbv[c] == fv && rbi[c] < fi)) { fv = rbv[c]; fi = rbi[c]; }
            sfinal[t] = fi;
        }
        __syncthreads();
    }

    // ---- epilogue: write quantized (NCHW) ----
    const int hl = tid & 63;          // token-local
    const int dq = tid >> 6;          // d-quarter 0..3
    const int qidx = sfinal[hl];
    const float* eq = emb + (size_t)qidx * D + dq * 16;
    float* op = out + (size_t)bb * (D * HWSZ) + (size_t)(dq * 16) * HWSZ + hwb + hl;
#pragma unroll
    for (int j0 = 0; j0 < 16; j0 += 4) {
        floatx4 e4 = *(const floatx4*)(eq + j0);
        op[(size_t)(j0 + 0) * HWSZ] = e4.x;
        op[(size_t)(j0 + 1) * HWSZ] = e4.y;
        op[(size_t)(j0 + 2) * HWSZ] = e4.z;
        op[(size_t)(j0 + 3) * HWSZ] = e4.w;
    }

    // ---- loss: wave reduce + one atomic per block ----
    for (int off = 32; off; off >>= 1) lacc += __shfl_xor(lacc, off);
    if (lane == 0) lred[w] = lacc;
    __syncthreads();
    if (tid == 0) atomicAdd(loss_acc, lred[0] + lred[1] + lred[2] + lred[3]);
}

__global__ void vq_finalize(const double* __restrict__ acc, float* __restrict__ out) {
    out[QUANT_ELEMS] = (float)(1.25 * (*acc) / (double)QUANT_ELEMS);
}

extern "C" void kernel_launch(void* const* d_in, const int* in_sizes, int n_in,
                              void* d_out, int out_size, void* d_ws, size_t ws_size,
                              hipStream_t stream) {
    const float* x = (const float*)d_in[0];
    const float* emb = (const float*)d_in[1];
    float* out = (float*)d_out;
    double* acc = (double*)d_ws;
    float* enorm_h = (float*)((char*)d_ws + 256);
    short8* G = (short8*)((char*)d_ws + 8192);   // 256 KB of frags

    vq_prep<<<16, TPB, 0, stream>>>(emb, acc, enorm_h, G);
    vq_main<<<NBLK, TPB, 0, stream>>>(x, emb, enorm_h, G, out, acc);
    vq_finalize<<<1, 1, 0, stream>>>(acc, out);
}